// Round 1
// baseline (616.317 us; speedup 1.0000x reference)
//
#include <hip/hip_runtime.h>
#include <stdint.h>

// Fused MHA for B=512,H=4,P=196,S=256,D=64.
// Key fact: out[b,o,p'] depends only on head h=p'/49 (12544=49*256), via
// M[pp][s] = av[4*pp + s/64][s&63] == flat avs (stride 64). One workgroup
// per (b,h): QKV proj (bf16 MFMA), full attention, out-proj for 49 pixels.

#define PPIX 196
#define SS   256
#define PPAD 224
#define NTT  14

typedef __attribute__((ext_vector_type(8))) short short8;
typedef __attribute__((ext_vector_type(4))) float f32x4;

// LDS layout (bytes):
#define SZ_REGA 29696                 // union: x-chunk [224][64] bf16 (28672) | ps 4x[16][232] (29696)
#define OFF_QS  (SZ_REGA)             // qs [224][72] bf16 (pitch-72 => 2-way-free banks)
#define SZ_QKS  (224*72*2)
#define OFF_KS  (OFF_QS + SZ_QKS)
#define OFF_VS  (OFF_KS + SZ_QKS)     // vs [64][232] bf16
#define SZ_VS   (64*232*2)
#define OFF_AVS (OFF_VS + SZ_VS)      // avs: 16384 bf16 (rows<196 valid; padded so GEMM3 reads stay in-bounds)
#define SZ_AVS  32768
#define SMEM_TOTAL (OFF_AVS + SZ_AVS) // 156672 <= 163840

static __device__ __forceinline__ uint16_t f2b(float f) {
  uint32_t u = __float_as_uint(f);
  return (uint16_t)((u + 0x7fffu + ((u >> 16) & 1u)) >> 16);  // RNE f32->bf16
}
static __device__ __forceinline__ f32x4 fz4() {
  f32x4 v; v[0] = 0.f; v[1] = 0.f; v[2] = 0.f; v[3] = 0.f; return v;
}

extern "C" __global__ void __launch_bounds__(256, 1)
mha_fused(const float* __restrict__ x,
          const float* __restrict__ wq, const float* __restrict__ bq,
          const float* __restrict__ wk, const float* __restrict__ bk,
          const float* __restrict__ wv, const float* __restrict__ bv,
          const float* __restrict__ wo, const float* __restrict__ bo,
          float* __restrict__ out) {
  extern __shared__ char smem[];
  uint16_t* const regA = (uint16_t*)(smem);
  uint16_t* const qs   = (uint16_t*)(smem + OFF_QS);
  uint16_t* const ks   = (uint16_t*)(smem + OFF_KS);
  uint16_t* const vsm  = (uint16_t*)(smem + OFF_VS);
  uint16_t* const avs  = (uint16_t*)(smem + OFF_AVS);

  const int bid = blockIdx.x;
  const int L = (bid & 7) * 256 + (bid >> 3);  // XCD-bijective swizzle (2048 = 8*256)
  const int b = L >> 2, h = L & 3;
  const int tid = threadIdx.x;
  const int w = tid >> 6;
  const int lane = tid & 63;
  const int g = lane >> 4;
  const int l15 = lane & 15;

  const float* xb = x + (size_t)b * (SS * PPIX);

  // ---------- Phase 1: QKV projection, C[192][224] = Wqkv_h[192][256] @ x[b] ----------
  f32x4 acc1[3][NTT];
#pragma unroll
  for (int mi = 0; mi < 3; ++mi)
#pragma unroll
    for (int nt = 0; nt < NTT; ++nt) acc1[mi][nt] = fz4();

  for (int cc = 0; cc < 4; ++cc) {
    __syncthreads();
    // stage x chunk transposed: regA[p][c ^ ((p&7)<<3)], rows p>=196 zeroed
    if (tid < PPAD) {
      const int p = tid;
      const int swz = (p & 7) << 3;
      uint32_t* dst = (uint32_t*)(regA + p * 64);
      if (p < PPIX) {
        const float* src = xb + (size_t)(cc * 64) * PPIX + p;
#pragma unroll
        for (int i = 0; i < 32; ++i) {
          float a0 = src[(2 * i) * PPIX];
          float a1 = src[(2 * i + 1) * PPIX];
          uint32_t pk = (uint32_t)f2b(a0) | ((uint32_t)f2b(a1) << 16);
          dst[((2 * i) ^ swz) >> 1] = pk;
        }
      } else {
#pragma unroll
        for (int i = 0; i < 32; ++i) dst[((2 * i) ^ swz) >> 1] = 0u;
      }
    }
    __syncthreads();
#pragma unroll
    for (int kt = 0; kt < 2; ++kt) {
      short8 afr[3];
#pragma unroll
      for (int mi = 0; mi < 3; ++mi) {
        const int mt = 3 * w + mi;          // wave w owns m-tiles 3w..3w+2 of 12
        const int chA = 16 * mt + l15;      // 0..191
        const int mat = chA >> 6;           // 0=q,1=k,2=v
        const int dA = chA & 63;
        const float* W = (mat == 0) ? wq : ((mat == 1) ? wk : wv);
        const float* srcA = W + (size_t)(h * 64 + dA) * SS + cc * 64 + kt * 32 + g * 8;
        f32x4 w0 = *(const f32x4*)srcA;
        f32x4 w1 = *(const f32x4*)(srcA + 4);
        short8 af;
#pragma unroll
        for (int j = 0; j < 4; ++j) { af[j] = (short)f2b(w0[j]); af[4 + j] = (short)f2b(w1[j]); }
        afr[mi] = af;
      }
#pragma unroll
      for (int nt = 0; nt < NTT; ++nt) {
        const int p = 16 * nt + l15;
        const int coff = (kt * 32 + g * 8) ^ ((p & 7) << 3);
        short8 bfr = *(const short8*)(regA + p * 64 + coff);
#pragma unroll
        for (int mi = 0; mi < 3; ++mi)
          acc1[mi][nt] = __builtin_amdgcn_mfma_f32_16x16x32_bf16(afr[mi], bfr, acc1[mi][nt], 0, 0, 0);
      }
    }
  }
  // write q/k/v (+bias) to LDS: q,k as [p][d] (pitch 72), v as [d][p] (pitch 232)
#pragma unroll
  for (int mi = 0; mi < 3; ++mi) {
    const int mt = 3 * w + mi;
    const int mat = (16 * mt) >> 6;
    const float* bias = (mat == 0) ? bq : ((mat == 1) ? bk : bv);
#pragma unroll
    for (int r = 0; r < 4; ++r) {
      const int ch = 16 * mt + 4 * g + r;
      const int d = ch - 64 * mat;
      const float bias_v = bias[h * 64 + d];
#pragma unroll
      for (int nt = 0; nt < NTT; ++nt) {
        const int p = 16 * nt + l15;
        const uint16_t val = f2b(acc1[mi][nt][r] + bias_v);
        if (mat == 2)      vsm[d * 232 + p] = val;
        else if (mat == 0) qs[p * 72 + d]   = val;
        else               ks[p * 72 + d]   = val;
      }
    }
  }
  __syncthreads();

  // ---------- Phase 2: attention (wave-private 16-row tiles) ----------
  uint16_t* const psw = regA + w * (16 * 232);
  for (int rt = w; rt < NTT; rt += 4) {
    if (16 * rt >= PPIX) continue;   // tile 13 all-pad
    f32x4 accA[NTT];
#pragma unroll
    for (int nt = 0; nt < NTT; ++nt) accA[nt] = fz4();
#pragma unroll
    for (int kt = 0; kt < 2; ++kt) {
      short8 a = *(const short8*)(qs + (16 * rt + l15) * 72 + kt * 32 + g * 8);
#pragma unroll
      for (int nt = 0; nt < NTT; ++nt) {
        short8 bfr = *(const short8*)(ks + (16 * nt + l15) * 72 + kt * 32 + g * 8);
        accA[nt] = __builtin_amdgcn_mfma_f32_16x16x32_bf16(a, bfr, accA[nt], 0, 0, 0);
      }
    }
    // scale 1/sqrt(64), mask cols>=196, row-softmax (rows live in 16-lane groups)
    float mx[4] = {-1e30f, -1e30f, -1e30f, -1e30f};
#pragma unroll
    for (int nt = 0; nt < NTT; ++nt) {
      const int col = 16 * nt + l15;
#pragma unroll
      for (int r = 0; r < 4; ++r) {
        float v = accA[nt][r] * 0.125f;
        if (col >= PPIX) v = -1e30f;
        accA[nt][r] = v;
        mx[r] = fmaxf(mx[r], v);
      }
    }
#pragma unroll
    for (int off = 1; off <= 8; off <<= 1)
#pragma unroll
      for (int r = 0; r < 4; ++r)
        mx[r] = fmaxf(mx[r], __shfl_xor(mx[r], off, 64));
    float sm[4] = {0.f, 0.f, 0.f, 0.f};
#pragma unroll
    for (int nt = 0; nt < NTT; ++nt)
#pragma unroll
      for (int r = 0; r < 4; ++r) {
        float e = exp2f((accA[nt][r] - mx[r]) * 1.44269504088896f);
        accA[nt][r] = e;
        sm[r] += e;
      }
#pragma unroll
    for (int off = 1; off <= 8; off <<= 1)
#pragma unroll
      for (int r = 0; r < 4; ++r)
        sm[r] += __shfl_xor(sm[r], off, 64);
    // round-trip P through per-wave LDS to re-fragment for PV
#pragma unroll
    for (int nt = 0; nt < NTT; ++nt)
#pragma unroll
      for (int r = 0; r < 4; ++r)
        psw[(4 * g + r) * 232 + 16 * nt + l15] = f2b(accA[nt][r]);
    f32x4 accV[4];
#pragma unroll
    for (int n = 0; n < 4; ++n) accV[n] = fz4();
#pragma unroll
    for (int kt = 0; kt < 7; ++kt) {
      short8 a = *(const short8*)(psw + l15 * 232 + kt * 32 + g * 8);
#pragma unroll
      for (int n = 0; n < 4; ++n) {
        short8 bfr = *(const short8*)(vsm + (16 * n + l15) * 232 + kt * 32 + g * 8);
        accV[n] = __builtin_amdgcn_mfma_f32_16x16x32_bf16(a, bfr, accV[n], 0, 0, 0);
      }
    }
    // normalize by row-sum, store avs[p][d ^ ((p>>2 & 7)<<3)] (stride 64 = flat M view)
#pragma unroll
    for (int r = 0; r < 4; ++r) {
      const int p = 16 * rt + 4 * g + r;
      if (p < PPIX) {
        const float inv = 1.0f / sm[r];
        const int swzp = ((p >> 2) & 7) << 3;
#pragma unroll
        for (int n = 0; n < 4; ++n) {
          const int d = 16 * n + l15;
          avs[p * 64 + (d ^ swzp)] = f2b(accV[n][r] * inv);
        }
      }
    }
  }
  __syncthreads();

  // ---------- Phase 3: out-proj C[256][49] = wo[256][256] @ M^T, M[pp][s]=avs_flat[256pp+s] ----------
  f32x4 accO[4][4];
#pragma unroll
  for (int mi = 0; mi < 4; ++mi)
#pragma unroll
    for (int ni = 0; ni < 4; ++ni) accO[mi][ni] = fz4();
#pragma unroll
  for (int kt = 0; kt < 8; ++kt) {
    short8 a[4];
#pragma unroll
    for (int mi = 0; mi < 4; ++mi) {
      const int o = 64 * w + 16 * mi + l15;
      const float* srcA = wo + (size_t)o * SS + kt * 32 + g * 8;
      f32x4 w0 = *(const f32x4*)srcA;
      f32x4 w1 = *(const f32x4*)(srcA + 4);
      short8 af;
#pragma unroll
      for (int j = 0; j < 4; ++j) { af[j] = (short)f2b(w0[j]); af[4 + j] = (short)f2b(w1[j]); }
      a[mi] = af;
    }
#pragma unroll
    for (int ni = 0; ni < 4; ++ni) {
      const int pp = 16 * ni + l15;
      const int s0 = kt * 32 + g * 8;
      const int idx = 256 * pp + ((s0 >> 6) << 6) + ((s0 & 63) ^ ((pp & 7) << 3));
      short8 bfr = *(const short8*)(avs + idx);   // pp>=49 reads garbage, discarded below
#pragma unroll
      for (int mi = 0; mi < 4; ++mi)
        accO[mi][ni] = __builtin_amdgcn_mfma_f32_16x16x32_bf16(a[mi], bfr, accO[mi][ni], 0, 0, 0);
    }
  }
#pragma unroll
  for (int mi = 0; mi < 4; ++mi) {
#pragma unroll
    for (int r = 0; r < 4; ++r) {
      const int o = 64 * w + 16 * mi + 4 * g + r;
      const float bias_v = bo[o];
      float* orow = out + ((size_t)b * SS + o) * PPIX + 49 * h;
#pragma unroll
      for (int ni = 0; ni < 4; ++ni) {
        const int pp = 16 * ni + l15;
        if (pp < 49) orow[pp] = accO[mi][ni][r] + bias_v;
      }
    }
  }
}

extern "C" void kernel_launch(void* const* d_in, const int* in_sizes, int n_in,
                              void* d_out, int out_size, void* d_ws, size_t ws_size,
                              hipStream_t stream) {
  (void)in_sizes; (void)n_in; (void)d_ws; (void)ws_size; (void)out_size;
  const float* x  = (const float*)d_in[0];
  const float* wq = (const float*)d_in[1];
  const float* bq = (const float*)d_in[2];
  const float* wk = (const float*)d_in[3];
  const float* bk = (const float*)d_in[4];
  const float* wv = (const float*)d_in[5];
  const float* bv = (const float*)d_in[6];
  const float* wo = (const float*)d_in[7];
  const float* bo = (const float*)d_in[8];
  float* out = (float*)d_out;
  (void)hipFuncSetAttribute(reinterpret_cast<const void*>(mha_fused),
                            hipFuncAttributeMaxDynamicSharedMemorySize, SMEM_TOTAL);
  mha_fused<<<dim3(2048), dim3(256), SMEM_TOTAL, stream>>>(x, wq, bq, wk, bk, wv, bv, wo, bo, out);
}

// Round 2
// 545.024 us; speedup vs baseline: 1.1308x; 1.1308x over previous
//
#include <hip/hip_runtime.h>
#include <stdint.h>

// Fused MHA for B=512,H=4,P=196,S=256,D=64.
// out[b,o,p'] depends only on head h=p'/49 (12544=49*256), via
// M[pp][s] = av[4*pp + s/64][s&63] == flat avs (stride 64). One workgroup
// per (b,h): QKV proj (bf16 MFMA), full attention, out-proj for 49 pixels.
// Round 2: 512 thr (8 waves, 2/SIMD), prepacked bf16 weights in d_ws,
// b128 staging writes, chunked per-wave psw.

#define PPIX 196
#define SS   256

typedef __attribute__((ext_vector_type(8))) short short8;
typedef __attribute__((ext_vector_type(4))) float f32x4;

// LDS layout (bytes):
#define PSWP    144                    // psw pitch (elems), 16B-aligned rows
#define SZ_UNI  36864                  // union: staging [224][64] bf16 (28672) | psw 8x[16][144] (36864)
#define OFF_QS  (SZ_UNI)               // qs [208][72] bf16
#define SZ_QK   (208*72*2)             // 29952
#define OFF_KS  (OFF_QS + SZ_QK)
#define OFF_VS  (OFF_KS + SZ_QK)       // vs [64][236] bf16 (V^T)
#define SZ_VS   (64*236*2)             // 30208
#define OFF_AVS (OFF_VS + SZ_VS)       // avs 12544 bf16
#define SZ_AVS  (12544*2)
#define SMEM_TOTAL (OFF_AVS + SZ_AVS)  // 152064 <= 163840

static __device__ __forceinline__ uint16_t f2b(float f) {
  uint32_t u = __float_as_uint(f);
  return (uint16_t)((u + 0x7fffu + ((u >> 16) & 1u)) >> 16);  // RNE f32->bf16
}
static __device__ __forceinline__ f32x4 fz4() {
  f32x4 v; v[0] = 0.f; v[1] = 0.f; v[2] = 0.f; v[3] = 0.f; return v;
}

template<bool PRE>
__global__ __launch_bounds__(512, 2)
void mha_fused(const float* __restrict__ x,
               const float* __restrict__ wq, const float* __restrict__ bq,
               const float* __restrict__ wk, const float* __restrict__ bk,
               const float* __restrict__ wv, const float* __restrict__ bv,
               const float* __restrict__ wo, const float* __restrict__ bo,
               const uint16_t* __restrict__ wpk,
               float* __restrict__ out) {
  extern __shared__ char smem[];
  uint16_t* const uni = (uint16_t*)(smem);
  uint16_t* const qs  = (uint16_t*)(smem + OFF_QS);
  uint16_t* const ks  = (uint16_t*)(smem + OFF_KS);
  uint16_t* const vsm = (uint16_t*)(smem + OFF_VS);
  uint16_t* const avs = (uint16_t*)(smem + OFF_AVS);

  const int bid = blockIdx.x;
  const int L = (bid & 7) * 256 + (bid >> 3);  // XCD-bijective swizzle (2048 = 8*256)
  const int b = L >> 2, h = L & 3;
  const int tid = threadIdx.x;
  const int w = tid >> 6;        // 0..7
  const int lane = tid & 63;
  const int g = lane >> 4;
  const int l15 = lane & 15;
  const int wm = w & 3;          // phase-1: 3 m-tiles (48 chans)
  const int wn = w >> 2;         // phase-1: 7 n-tiles (112 pixels)

  const float* xb = x + (size_t)b * (SS * PPIX);

  // ---------- Phase 1: QKV projection, C[192ch][224p] ----------
  f32x4 acc1[3][7];
#pragma unroll
  for (int mi = 0; mi < 3; ++mi)
#pragma unroll
    for (int nt = 0; nt < 7; ++nt) acc1[mi][nt] = fz4();

  const int prow = tid >> 1;     // 2 threads per pixel-row
  const int phalf = tid & 1;

  for (int cc = 0; cc < 4; ++cc) {
    __syncthreads();
    // A-frag prefetch for this cc (global; latency hides under staging+barrier)
    short8 afr[2][3];
#pragma unroll
    for (int kt = 0; kt < 2; ++kt)
#pragma unroll
      for (int mi = 0; mi < 3; ++mi) {
        const int chA = 48 * wm + 16 * mi + l15;
        const int mat = chA >> 6, dA = chA & 63;
        const int col = cc * 64 + kt * 32 + g * 8;
        if (PRE) {
          afr[kt][mi] = *(const short8*)(wpk + ((size_t)(mat * 256 + h * 64 + dA)) * SS + col);
        } else {
          const float* W = (mat == 0) ? wq : ((mat == 1) ? wk : wv);
          const float* s = W + (size_t)(h * 64 + dA) * SS + col;
          f32x4 w0 = *(const f32x4*)s, w1 = *(const f32x4*)(s + 4);
          short8 af;
#pragma unroll
          for (int j = 0; j < 4; ++j) { af[j] = (short)f2b(w0[j]); af[4 + j] = (short)f2b(w1[j]); }
          afr[kt][mi] = af;
        }
      }
    // stage x chunk transposed into uni[p][c ^ ((p&7)<<3)], b128 writes
    if (prow < 224) {
      const int swz = (prow & 7) << 3;
      uint16_t* dstrow = uni + prow * 64;
      if (prow < PPIX) {
        const float* src = xb + (size_t)(cc * 64 + phalf * 32) * PPIX + prow;
#pragma unroll
        for (int cb = 0; cb < 4; ++cb) {
          short8 pk;
#pragma unroll
          for (int t = 0; t < 8; ++t) pk[t] = (short)f2b(src[(cb * 8 + t) * PPIX]);
          *(short8*)(dstrow + ((phalf * 32 + cb * 8) ^ swz)) = pk;
        }
      } else {
        short8 z;
#pragma unroll
        for (int t = 0; t < 8; ++t) z[t] = 0;
#pragma unroll
        for (int cb = 0; cb < 4; ++cb)
          *(short8*)(dstrow + ((phalf * 32 + cb * 8) ^ swz)) = z;
      }
    }
    __syncthreads();
#pragma unroll
    for (int kt = 0; kt < 2; ++kt)
#pragma unroll
      for (int ntl = 0; ntl < 7; ++ntl) {
        const int p = 16 * (7 * wn + ntl) + l15;
        const int coff = (kt * 32 + g * 8) ^ ((p & 7) << 3);
        short8 bfr = *(const short8*)(uni + p * 64 + coff);
#pragma unroll
        for (int mi = 0; mi < 3; ++mi)
          acc1[mi][ntl] = __builtin_amdgcn_mfma_f32_16x16x32_bf16(afr[kt][mi], bfr, acc1[mi][ntl], 0, 0, 0);
      }
  }
  // write q/k (as [p][d], pitch 72) and v (as V^T [d][p], pitch 236) + bias
#pragma unroll
  for (int mi = 0; mi < 3; ++mi) {
    const int ch0 = 48 * wm + 16 * mi;
    const int mat = ch0 >> 6;
    const float* bias = (mat == 0) ? bq : ((mat == 1) ? bk : bv);
#pragma unroll
    for (int r = 0; r < 4; ++r) {
      const int ch = ch0 + 4 * g + r;
      const int d = ch & 63;
      const float bias_v = bias[h * 64 + d];
#pragma unroll
      for (int ntl = 0; ntl < 7; ++ntl) {
        const int p = 16 * (7 * wn + ntl) + l15;
        const uint16_t val = f2b(acc1[mi][ntl][r] + bias_v);
        if (mat == 2)      vsm[d * 236 + p] = val;
        else if (mat == 0) { if (p < 208) qs[p * 72 + d] = val; }
        else               { if (p < 208) ks[p * 72 + d] = val; }
      }
    }
  }
  __syncthreads();

  // ---------- Phase 2: attention, 13 row-tiles over 8 waves ----------
  uint16_t* const psw = uni + w * (16 * PSWP);
#pragma unroll 1
  for (int round = 0; round < 2; ++round) {
    const int rt = 8 * round + w;
    if (rt > 12) continue;
    f32x4 accA[14];
#pragma unroll
    for (int nt = 0; nt < 14; ++nt) accA[nt] = fz4();
#pragma unroll
    for (int kt = 0; kt < 2; ++kt) {
      short8 a = *(const short8*)(qs + (16 * rt + l15) * 72 + kt * 32 + g * 8);
#pragma unroll
      for (int nt = 0; nt < 14; ++nt) {
        short8 bfr = *(const short8*)(ks + (16 * nt + l15) * 72 + kt * 32 + g * 8);
        accA[nt] = __builtin_amdgcn_mfma_f32_16x16x32_bf16(a, bfr, accA[nt], 0, 0, 0);
      }
    }
    // mask cols>=196 on raw logits; softmax with folded 1/8 * log2e scale
    float mx[4] = {-3e38f, -3e38f, -3e38f, -3e38f};
#pragma unroll
    for (int nt = 0; nt < 14; ++nt) {
      const int col = 16 * nt + l15;
#pragma unroll
      for (int r = 0; r < 4; ++r) {
        float v = accA[nt][r];
        if (col >= PPIX) v = -3e38f;
        accA[nt][r] = v;
        mx[r] = fmaxf(mx[r], v);
      }
    }
#pragma unroll
    for (int off = 1; off <= 8; off <<= 1)
#pragma unroll
      for (int r = 0; r < 4; ++r)
        mx[r] = fmaxf(mx[r], __shfl_xor(mx[r], off, 64));
    float sm[4] = {0.f, 0.f, 0.f, 0.f};
    const float cs = 0.125f * 1.44269504088896f;
#pragma unroll
    for (int nt = 0; nt < 14; ++nt)
#pragma unroll
      for (int r = 0; r < 4; ++r) {
        float e = exp2f((accA[nt][r] - mx[r]) * cs);
        accA[nt][r] = e;
        sm[r] += e;
      }
#pragma unroll
    for (int off = 1; off <= 8; off <<= 1)
#pragma unroll
      for (int r = 0; r < 4; ++r)
        sm[r] += __shfl_xor(sm[r], off, 64);

    f32x4 accV[4];
#pragma unroll
    for (int n = 0; n < 4; ++n) accV[n] = fz4();
    // chunk 0: keys 0..127 through wave-private psw (XOR-swizzled)
#pragma unroll
    for (int nt = 0; nt < 8; ++nt)
#pragma unroll
      for (int r = 0; r < 4; ++r) {
        const int row = 4 * g + r;
        psw[row * PSWP + ((16 * nt + l15) ^ ((row & 7) << 3))] = f2b(accA[nt][r]);
      }
#pragma unroll
    for (int kt = 0; kt < 4; ++kt) {
      short8 a = *(const short8*)(psw + l15 * PSWP + ((kt * 32 + g * 8) ^ ((l15 & 7) << 3)));
#pragma unroll
      for (int n = 0; n < 4; ++n) {
        short8 bfr = *(const short8*)(vsm + (16 * n + l15) * 236 + kt * 32 + g * 8);
        accV[n] = __builtin_amdgcn_mfma_f32_16x16x32_bf16(a, bfr, accV[n], 0, 0, 0);
      }
    }
    // chunk 1: keys 128..223
#pragma unroll
    for (int nt = 8; nt < 14; ++nt)
#pragma unroll
      for (int r = 0; r < 4; ++r) {
        const int row = 4 * g + r;
        psw[row * PSWP + ((16 * (nt - 8) + l15) ^ ((row & 7) << 3))] = f2b(accA[nt][r]);
      }
#pragma unroll
    for (int kt = 0; kt < 3; ++kt) {
      short8 a = *(const short8*)(psw + l15 * PSWP + ((kt * 32 + g * 8) ^ ((l15 & 7) << 3)));
#pragma unroll
      for (int n = 0; n < 4; ++n) {
        short8 bfr = *(const short8*)(vsm + (16 * n + l15) * 236 + 128 + kt * 32 + g * 8);
        accV[n] = __builtin_amdgcn_mfma_f32_16x16x32_bf16(a, bfr, accV[n], 0, 0, 0);
      }
    }
    // normalize, store avs[p][d ^ ((p>>2 & 7)<<3)] (stride 64 = flat M view)
#pragma unroll
    for (int r = 0; r < 4; ++r) {
      const int p = 16 * rt + 4 * g + r;
      if (p < PPIX) {
        const float inv = 1.0f / sm[r];
        const int swzp = ((p >> 2) & 7) << 3;
#pragma unroll
        for (int n = 0; n < 4; ++n) {
          const int d = 16 * n + l15;
          avs[p * 64 + (d ^ swzp)] = f2b(accV[n][r] * inv);
        }
      }
    }
  }
  __syncthreads();

  // ---------- Phase 3: out-proj C[256][49] = wo[256][256] @ M^T ----------
  f32x4 accO[2][4];
#pragma unroll
  for (int mi = 0; mi < 2; ++mi)
#pragma unroll
    for (int ni = 0; ni < 4; ++ni) accO[mi][ni] = fz4();
#pragma unroll
  for (int kt = 0; kt < 8; ++kt) {
    short8 a[2];
#pragma unroll
    for (int mi = 0; mi < 2; ++mi) {
      const int o = 32 * w + 16 * mi + l15;
      if (PRE) {
        a[mi] = *(const short8*)(wpk + 3 * 65536 + (size_t)o * SS + kt * 32 + g * 8);
      } else {
        const float* srcA = wo + (size_t)o * SS + kt * 32 + g * 8;
        f32x4 w0 = *(const f32x4*)srcA;
        f32x4 w1 = *(const f32x4*)(srcA + 4);
        short8 af;
#pragma unroll
        for (int j = 0; j < 4; ++j) { af[j] = (short)f2b(w0[j]); af[4 + j] = (short)f2b(w1[j]); }
        a[mi] = af;
      }
    }
#pragma unroll
    for (int ni = 0; ni < 4; ++ni) {
      const int pp = 16 * ni + l15;
      const int pmin = pp < 49 ? pp : 48;
      const int s0 = kt * 32 + g * 8;
      const int idx = 256 * pmin + ((s0 >> 6) << 6) + ((s0 & 63) ^ ((pmin & 7) << 3));
      short8 bfr = *(const short8*)(avs + idx);
#pragma unroll
      for (int mi = 0; mi < 2; ++mi)
        accO[mi][ni] = __builtin_amdgcn_mfma_f32_16x16x32_bf16(a[mi], bfr, accO[mi][ni], 0, 0, 0);
    }
  }
#pragma unroll
  for (int mi = 0; mi < 2; ++mi) {
#pragma unroll
    for (int r = 0; r < 4; ++r) {
      const int o = 32 * w + 16 * mi + 4 * g + r;
      const float bias_v = bo[o];
      float* orow = out + ((size_t)b * SS + o) * PPIX + 49 * h;
#pragma unroll
      for (int ni = 0; ni < 4; ++ni) {
        const int pp = 16 * ni + l15;
        if (pp < 49) orow[pp] = accO[mi][ni][r] + bias_v;
      }
    }
  }
}

// f32 -> bf16 prepack of the four 256x256 weight matrices into d_ws.
__global__ __launch_bounds__(256)
void prepack_w(const float* __restrict__ wq, const float* __restrict__ wk,
               const float* __restrict__ wv, const float* __restrict__ wo,
               uint16_t* __restrict__ ws) {
  const int t = blockIdx.x * 256 + threadIdx.x;  // 32768 threads x 8 elems
  const int mat = t >> 13;
  const int off = (t & 8191) << 3;
  const float* src = (mat == 0) ? wq : ((mat == 1) ? wk : ((mat == 2) ? wv : wo));
  f32x4 a = *(const f32x4*)(src + off);
  f32x4 b = *(const f32x4*)(src + off + 4);
  short8 o;
#pragma unroll
  for (int j = 0; j < 4; ++j) { o[j] = (short)f2b(a[j]); o[4 + j] = (short)f2b(b[j]); }
  *(short8*)(ws + ((size_t)mat << 16) + off) = o;
}

extern "C" void kernel_launch(void* const* d_in, const int* in_sizes, int n_in,
                              void* d_out, int out_size, void* d_ws, size_t ws_size,
                              hipStream_t stream) {
  (void)in_sizes; (void)n_in; (void)out_size;
  const float* x  = (const float*)d_in[0];
  const float* wq = (const float*)d_in[1];
  const float* bq = (const float*)d_in[2];
  const float* wk = (const float*)d_in[3];
  const float* bk = (const float*)d_in[4];
  const float* wv = (const float*)d_in[5];
  const float* bv = (const float*)d_in[6];
  const float* wo = (const float*)d_in[7];
  const float* bo = (const float*)d_in[8];
  float* out = (float*)d_out;
  uint16_t* ws16 = (uint16_t*)d_ws;

  const bool pre = (d_ws != nullptr) && (ws_size >= (size_t)4 * 65536 * sizeof(uint16_t));
  if (pre) {
    (void)hipFuncSetAttribute(reinterpret_cast<const void*>(&mha_fused<true>),
                              hipFuncAttributeMaxDynamicSharedMemorySize, SMEM_TOTAL);
    prepack_w<<<dim3(128), dim3(256), 0, stream>>>(wq, wk, wv, wo, ws16);
    mha_fused<true><<<dim3(2048), dim3(512), SMEM_TOTAL, stream>>>(
        x, wq, bq, wk, bk, wv, bv, wo, bo, ws16, out);
  } else {
    (void)hipFuncSetAttribute(reinterpret_cast<const void*>(&mha_fused<false>),
                              hipFuncAttributeMaxDynamicSharedMemorySize, SMEM_TOTAL);
    mha_fused<false><<<dim3(2048), dim3(512), SMEM_TOTAL, stream>>>(
        x, wq, bq, wk, bk, wv, bv, wo, bo, ws16, out);
  }
}